// Round 1
// baseline (895.710 us; speedup 1.0000x reference)
//
#include <hip/hip_runtime.h>

// FNO2d: full-mode spectral conv == spatial pair-mixing (no FFT needed).
// h layout in ws: channel-last, h[((b*65536 + r*256 + c))*128 + d], fp32.
#define WS_H_FLOATS 33554432   // 4*256*256*128
#define W2_FLOATS   131072     // 4 layers * 2 (E,F) * 128*128
#define RB_FLOATS   131072     // 4 layers * 256 cols * 128 ch

__device__ __forceinline__ float gelu_f(float x) {
    return 0.5f * x * (1.0f + erff(x * 0.7071067811865476f));
}

// W2[l][which][i][o] = 0.5*(cw[l][o][i] + (which? wi : wr)[l][i][o])
__global__ void prep_weights(const float* __restrict__ wr, const float* __restrict__ wi,
                             const float* __restrict__ cw, float* __restrict__ W2) {
    int idx = blockIdx.x * 256 + threadIdx.x;       // 131072
    int l = idx >> 15;
    int which = (idx >> 14) & 1;
    int i = (idx >> 7) & 127;
    int o = idx & 127;
    const float* w = which ? wi : wr;
    W2[idx] = 0.5f * (cw[(l << 14) + (o << 7) + i] + w[(l << 14) + (i << 7) + o]);
}

// RB[l][c][o]: spatial map of the per-frequency constant bias (row n1==0 only).
// c==0: br[o];  c!=0: -bi[o] * (1/128) * sum_{k=1..127} sin(pi*k*c/128)
__global__ void prep_rowbias(const float* __restrict__ br, const float* __restrict__ bi,
                             float* __restrict__ RB) {
    int idx = blockIdx.x * 256 + threadIdx.x;       // 131072 = 4*256*128
    int l = idx >> 15;
    int c = (idx >> 7) & 255;
    int o = idx & 127;
    float v;
    if (c == 0) {
        v = br[(l << 7) + o];
    } else {
        float s = 0.0f;
        for (int k = 1; k < 128; k++) {
            int m = (k * c) & 255;                  // sin(pi*m/128) has period m mod 256
            s += sinf(0.024543692952156857f * (float)m);  // pi/128
        }
        v = -bi[(l << 7) + o] * s * 0.0078125f;
    }
    RB[idx] = v;
}

// h[b,p,d] = gelu(sum_c x[b,c,p]*w[c,d] + bvec[d]); channel-last output
__global__ void lin_in_kernel(const float* __restrict__ x, const float* __restrict__ w,
                              const float* __restrict__ bvec, float* __restrict__ h) {
    int g = blockIdx.x * 256 + threadIdx.x;         // 33554432
    int d = g & 127;
    int bp = g >> 7;
    int p = bp & 65535;
    int b = bp >> 16;
    const float* xb = x + (b * 3) * 65536 + p;
    float acc = bvec[d];
    acc = fmaf(xb[0],      w[d],       acc);
    acc = fmaf(xb[65536],  w[128 + d], acc);
    acc = fmaf(xb[131072], w[256 + d], acc);
    h[g] = gelu_f(acc);
}

// One FNO layer, in place.  Blocks 0..4095: 32 pixel-pairs each.
// u = E'^T(h_p+h_q), v = F'^T(h_p-h_q); out_p = gelu(u+v+bias), out_q = gelu(u-v+bias).
// Pairing: class A (r in [1,127], 8 col tiles) pairs row r with 256-r.
//          class B (r in {0,128}, 4 col tiles starting at col 1) pairs within the row.
// Blocks 4096..4099: self-paired pixels (b,0,0) and (b,128,0).
__global__ __launch_bounds__(256, 3) void layer_kernel(float* __restrict__ h,
        const float* __restrict__ Wg,   // W2 + l*32768: [2][128][128]
        const float* __restrict__ RBl,  // RB + l*32768: [256][128]
        const float* __restrict__ cbl)  // cb + l*128
{
    __shared__ float As[128 * 65];          // As[k*65 + col]: col<32 = s_j[k], col>=32 = d_j[k]
    __shared__ float Ws[2 * 16 * 128];      // chunk of E' (which 0) and F' (which 1)

    int bid = blockIdx.x;
    int tid = threadIdx.x;

    if (bid >= 4096) {
        // --- special: self-paired pixels (0,0) and (128,0); out = E^T h = 2*E'^T h ---
        int b2 = bid - 4096;
        int base0 = ((b2 << 16)) << 7;
        int base1 = ((b2 << 16) + (128 << 8)) << 7;
        if (tid < 128) As[tid] = h[base0 + tid];
        else           As[tid] = h[base1 + (tid - 128)];
        __syncthreads();
        int o = tid & 127;
        const float* colv = (tid < 128) ? As : (As + 128);
        float acc = 0.0f;
        for (int i = 0; i < 128; i++) acc = fmaf(Wg[(i << 7) + o], colv[i], acc);
        acc = 2.0f * acc + cbl[o];
        if (tid < 128) acc += RBl[o];       // row 0, col 0 gets br
        float val = gelu_f(acc);
        if (tid < 128) h[base0 + o] = val;
        else           h[base1 + o] = val;
        return;
    }

    int b = bid >> 10;
    int rem = bid & 1023;
    int r, c0, rq;
    bool rowzero;
    if (rem < 1016) {
        r = 1 + (rem >> 3);
        c0 = (rem & 7) << 5;
        rq = 256 - r;
        rowzero = false;
    } else {
        int idx2 = rem - 1016;
        r = (idx2 < 4) ? 0 : 128;
        c0 = 1 + ((idx2 & 3) << 5);
        rq = r;
        rowzero = (r == 0);
    }

    // ---- stage s = hp+hq, d = hp-hq into LDS (transposed, stride 65) ----
    {
        int j = tid >> 3;                   // pair 0..31
        int seg = tid & 7;                  // k segment of 16
        int cp = c0 + j;
        int cq = (256 - cp) & 255;
        int k0 = seg << 4;
        const float4* hp4 = (const float4*)(h + (((b << 16) + (r << 8) + cp) << 7) + k0);
        const float4* hq4 = (const float4*)(h + (((b << 16) + (rq << 8) + cq) << 7) + k0);
        float4 P[4] = {hp4[0], hp4[1], hp4[2], hp4[3]};
        float4 Q[4] = {hq4[0], hq4[1], hq4[2], hq4[3]};
        #pragma unroll
        for (int m = 0; m < 4; m++) {
            float ps[4] = {P[m].x, P[m].y, P[m].z, P[m].w};
            float qs[4] = {Q[m].x, Q[m].y, Q[m].z, Q[m].w};
            #pragma unroll
            for (int n = 0; n < 4; n++) {
                int k = k0 + (m << 2) + n;
                As[k * 65 + j]      = ps[n] + qs[n];
                As[k * 65 + 32 + j] = ps[n] - qs[n];
            }
        }
    }

    // ---- GEMM: C[64 rows][128 oc] = As[128 k][64 rows]^T x W[128 k][128 oc] ----
    int rg = tid & 15;                      // rows 4rg..4rg+3 (rg<8: s rows -> E'; rg>=8: d rows -> F')
    int og = tid >> 4;                      // oc 8og..8og+7
    float acc[4][8];
    #pragma unroll
    for (int rr = 0; rr < 4; rr++)
        #pragma unroll
        for (int cc = 0; cc < 8; cc++) acc[rr][cc] = 0.0f;

    const int wsel = (rg < 8) ? 0 : 2048;   // LDS offset into Ws for E'/F'
    for (int kc = 0; kc < 8; kc++) {
        __syncthreads();
        // load 16-k chunk of both E' and F': 4096 floats, 16 per thread
        {
            int base = tid << 4;
            int which = base >> 11;
            int rem3 = base & 2047;
            int kk = rem3 >> 7;
            int oo = rem3 & 127;
            const float4* src = (const float4*)(Wg + which * 16384 + ((kc * 16 + kk) << 7) + oo);
            float4* dst = (float4*)(Ws + base);
            dst[0] = src[0]; dst[1] = src[1]; dst[2] = src[2]; dst[3] = src[3];
        }
        __syncthreads();
        const float* WsSel = Ws + wsel;
        #pragma unroll
        for (int kk2 = 0; kk2 < 16; kk2++) {
            float4 a = *(const float4*)&As[(kc * 16 + kk2) * 65 + (rg << 2)];
            const float* wrow = WsSel + (kk2 << 7) + (og << 3);
            float4 w0 = *(const float4*)wrow;
            float4 w1 = *(const float4*)(wrow + 4);
            float av[4] = {a.x, a.y, a.z, a.w};
            float wv[8] = {w0.x, w0.y, w0.z, w0.w, w1.x, w1.y, w1.z, w1.w};
            #pragma unroll
            for (int rr = 0; rr < 4; rr++)
                #pragma unroll
                for (int cc = 0; cc < 8; cc++)
                    acc[rr][cc] = fmaf(av[rr], wv[cc], acc[rr][cc]);
        }
    }

    // ---- epilogue: exchange u/v via shfl_xor(8), add bias, gelu, store ----
    const int isLow = (rg < 8);
    const int pr = isLow ? rg : (rg - 8);
    #pragma unroll
    for (int rr = 0; rr < 4; rr++) {
        int pair = 4 * pr + rr;
        float pre[8];
        #pragma unroll
        for (int cc = 0; cc < 8; cc++) {
            float other = __shfl_xor(acc[rr][cc], 8, 64);
            pre[cc] = isLow ? (acc[rr][cc] + other) : (other - acc[rr][cc]);
        }
        int col = isLow ? (c0 + pair) : ((256 - (c0 + pair)) & 255);
        int row = isLow ? r : rq;
        float* outp = h + (((b << 16) + (row << 8) + col) << 7) + (og << 3);
        const float* cbp = cbl + (og << 3);
        #pragma unroll
        for (int cc = 0; cc < 8; cc++) {
            float v2 = pre[cc] + cbp[cc];
            if (rowzero) v2 += RBl[(col << 7) + (og << 3) + cc];
            pre[cc] = gelu_f(v2);
        }
        ((float4*)outp)[0] = make_float4(pre[0], pre[1], pre[2], pre[3]);
        ((float4*)outp)[1] = make_float4(pre[4], pre[5], pre[6], pre[7]);
    }
}

// y[bp] = gelu(sum_d h[bp][d]*wo[d] + bo); one wave per pixel chunk
__global__ void lin_out_kernel(const float* __restrict__ h, const float* __restrict__ wo,
                               const float* __restrict__ bo, float* __restrict__ out) {
    int gtid = blockIdx.x * 256 + threadIdx.x;
    int wave = gtid >> 6;
    int lane = threadIdx.x & 63;
    float w0 = wo[lane * 2], w1 = wo[lane * 2 + 1];
    float bb = bo[0];
    int px0 = wave * 32;
    for (int px = px0; px < px0 + 32; px++) {
        const float2 v = *(const float2*)(h + (px << 7) + lane * 2);
        float partial = fmaf(v.x, w0, v.y * w1);
        #pragma unroll
        for (int m = 32; m >= 1; m >>= 1) partial += __shfl_xor(partial, m, 64);
        if (lane == 0) out[px] = gelu_f(partial + bb);
    }
}

extern "C" void kernel_launch(void* const* d_in, const int* in_sizes, int n_in,
                              void* d_out, int out_size, void* d_ws, size_t ws_size,
                              hipStream_t stream) {
    const float* x         = (const float*)d_in[0];
    const float* lin_in_w  = (const float*)d_in[1];
    const float* lin_in_b  = (const float*)d_in[2];
    const float* wr        = (const float*)d_in[3];
    const float* wi        = (const float*)d_in[4];
    const float* br        = (const float*)d_in[5];
    const float* bi        = (const float*)d_in[6];
    const float* cw        = (const float*)d_in[7];
    const float* cb        = (const float*)d_in[8];
    const float* lin_out_w = (const float*)d_in[9];
    const float* lin_out_b = (const float*)d_in[10];
    float* out = (float*)d_out;

    if (ws_size < (size_t)(WS_H_FLOATS + W2_FLOATS + RB_FLOATS) * sizeof(float)) return;
    float* ws = (float*)d_ws;
    float* h  = ws;
    float* W2 = ws + WS_H_FLOATS;
    float* RB = W2 + W2_FLOATS;

    prep_weights<<<512, 256, 0, stream>>>(wr, wi, cw, W2);
    prep_rowbias<<<512, 256, 0, stream>>>(br, bi, RB);
    lin_in_kernel<<<131072, 256, 0, stream>>>(x, lin_in_w, lin_in_b, h);
    for (int l = 0; l < 4; l++) {
        layer_kernel<<<4100, 256, 0, stream>>>(h, W2 + l * 32768, RB + l * 32768, cb + l * 128);
    }
    lin_out_kernel<<<2048, 256, 0, stream>>>(h, lin_out_w, lin_out_b, out);
}

// Round 3
// 486.631 us; speedup vs baseline: 1.8406x; 1.8406x over previous
//
#include <hip/hip_runtime.h>

// FNO2d: full-mode spectral conv == spatial pair-mixing (no FFT needed).
// Round 3: fix Wbuf chunk stride bug (kc*1024 -> kc*2048 uint4).
// h layout in ws: channel-last, h[((b*65536 + r*256 + c))*128 + d], fp32.
#define WS_H_FLOATS 33554432   // 4*256*256*128
#define W2_FLOATS   131072     // 4 layers * 2 (E,F) * 128*128  (fp32, special path)
#define RB_FLOATS   131072     // 4 layers * 256 cols * 128 ch
#define WBF_USHORTS 262144     // 4 layers * 4 chunks * 16384 (split-bf16 B-operand layout)

typedef short s8v __attribute__((ext_vector_type(8)));   // 8 bf16 (4 VGPRs)
typedef float f4v __attribute__((ext_vector_type(4)));   // MFMA acc

__device__ __forceinline__ float gelu_f(float x) {
    return 0.5f * x * (1.0f + erff(x * 0.7071067811865476f));
}

__device__ __forceinline__ unsigned short bf16_rne(float v) {
    unsigned u = __float_as_uint(v);
    unsigned r = u + 0x7FFFu + ((u >> 16) & 1u);
    return (unsigned short)(r >> 16);
}
__device__ __forceinline__ float bf16_tof(unsigned short x) {
    return __uint_as_float(((unsigned)x) << 16);
}

// W2[l][which][i][o] = 0.5*(cw[l][o][i] + (which? wi : wr)[l][i][o])  (fp32, special path)
__global__ void prep_weights(const float* __restrict__ wr, const float* __restrict__ wi,
                             const float* __restrict__ cw, float* __restrict__ W2) {
    int idx = blockIdx.x * 256 + threadIdx.x;       // 131072
    int l = idx >> 15;
    int which = (idx >> 14) & 1;
    int i = (idx >> 7) & 127;
    int o = idx & 127;
    const float* w = which ? wi : wr;
    W2[idx] = 0.5f * (cw[(l << 14) + (o << 7) + i] + w[(l << 14) + (i << 7) + o]);
}

// Split-bf16 weights in B-operand layout.
// Wbf[l][kc][mat][half][quad][col][j]; k = kc*32 + quad*8 + j (input ch), col = out ch.
__global__ void prep_weights_bf16(const float* __restrict__ wr, const float* __restrict__ wi,
                                  const float* __restrict__ cw, unsigned short* __restrict__ Wbf) {
    int t = blockIdx.x * 256 + threadIdx.x;         // 131072 = 4*4*2*4*128*8
    int j    = t & 7;
    int col  = (t >> 3) & 127;
    int quad = (t >> 10) & 3;
    int m2   = (t >> 12) & 1;
    int kc   = (t >> 13) & 3;
    int l    = t >> 15;
    int k = kc * 32 + quad * 8 + j;
    const float* w = m2 ? wi : wr;
    float v = 0.5f * (cw[(l << 14) + (col << 7) + k] + w[(l << 14) + (k << 7) + col]);
    unsigned short hi = bf16_rne(v);
    unsigned short lo = bf16_rne(v - bf16_tof(hi));
    int base = (l * 4 + kc) * 16384;
    int idx_hi = base + (((m2 * 2 + 0) * 4 + quad) * 128 + col) * 8 + j;
    int idx_lo = base + (((m2 * 2 + 1) * 4 + quad) * 128 + col) * 8 + j;
    Wbf[idx_hi] = hi;
    Wbf[idx_lo] = lo;
}

// RB[l][c][o]: spatial map of the per-frequency constant bias (row n1==0 only).
__global__ void prep_rowbias(const float* __restrict__ br, const float* __restrict__ bi,
                             float* __restrict__ RB) {
    int idx = blockIdx.x * 256 + threadIdx.x;       // 131072 = 4*256*128
    int l = idx >> 15;
    int c = (idx >> 7) & 255;
    int o = idx & 127;
    float v;
    if (c == 0) {
        v = br[(l << 7) + o];
    } else {
        float s = 0.0f;
        for (int k = 1; k < 128; k++) {
            int m = (k * c) & 255;
            s += sinf(0.024543692952156857f * (float)m);  // pi/128
        }
        v = -bi[(l << 7) + o] * s * 0.0078125f;
    }
    RB[idx] = v;
}

// h[b,p,d] = gelu(sum_c x[b,c,p]*w[c,d] + bvec[d]); channel-last output
__global__ void lin_in_kernel(const float* __restrict__ x, const float* __restrict__ w,
                              const float* __restrict__ bvec, float* __restrict__ h) {
    int g = blockIdx.x * 256 + threadIdx.x;         // 33554432
    int d = g & 127;
    int bp = g >> 7;
    int p = bp & 65535;
    int b = bp >> 16;
    const float* xb = x + (b * 3) * 65536 + p;
    float acc = bvec[d];
    acc = fmaf(xb[0],      w[d],       acc);
    acc = fmaf(xb[65536],  w[128 + d], acc);
    acc = fmaf(xb[131072], w[256 + d], acc);
    h[g] = gelu_f(acc);
}

// Abuf layout (ushort): [sd2][kt4][half2][pair32][qj32]; qj = quad*8 + j (= k within chunk)
#define A_IDX(sd, kt, hf, pair, qj) (((((sd)*4 + (kt))*2 + (hf))*32 + (pair))*32 + (qj))
// Wbuf layout (ushort): [mat2][half2][quad4][col128][j8]
#define W_IDX(m2, hf, quad, col) (((((m2)*2 + (hf))*4 + (quad))*128 + (col))*8)

// One FNO layer, in place, MFMA version.
// Blocks 0..4095: 32 pixel-pairs; u = E'^T(hp+hq), v = F'^T(hp-hq);
// out_p = gelu(u+v+bias), out_q = gelu(u-v+bias).
// Blocks 4096..4099: self-paired pixels (b,0,0),(b,128,0) via fp32 path.
__global__ __launch_bounds__(256, 2) void layer_mfma(float* __restrict__ h,
        const float* __restrict__ W2l,          // fp32 E' for special blocks: W2 + l*32768
        const unsigned short* __restrict__ Wbl, // Wbf + l*4*16384
        const float* __restrict__ RBl,          // RB + l*32768
        const float* __restrict__ cbl)          // cb + l*128
{
    __shared__ unsigned short Abuf[16384];   // 32 KB
    __shared__ unsigned short Wbuf[16384];   // 32 KB

    int bid = blockIdx.x;
    int tid = threadIdx.x;

    if (bid >= 4096) {
        // --- special: self-paired pixels (0,0) and (128,0); out = 2*E'^T h + bias ---
        float* Asf = (float*)Abuf;
        int b2 = bid - 4096;
        int base0 = (b2 << 16) << 7;
        int base1 = ((b2 << 16) + (128 << 8)) << 7;
        if (tid < 128) Asf[tid] = h[base0 + tid];
        else           Asf[tid] = h[base1 + (tid - 128)];
        __syncthreads();
        int o = tid & 127;
        const float* colv = (tid < 128) ? Asf : (Asf + 128);
        float acc = 0.0f;
        for (int i = 0; i < 128; i++) acc = fmaf(W2l[(i << 7) + o], colv[i], acc);
        acc = 2.0f * acc + cbl[o];
        if (tid < 128) acc += RBl[o];       // row 0, col 0 gets br-derived bias
        float val = gelu_f(acc);
        if (tid < 128) h[base0 + o] = val;
        else           h[base1 + o] = val;
        return;
    }

    int b = bid >> 10;
    int rem = bid & 1023;
    int r, c0, rq;
    bool rowzero;
    if (rem < 1016) {
        r = 1 + (rem >> 3);
        c0 = (rem & 7) << 5;
        rq = 256 - r;
        rowzero = false;
    } else {
        int idx2 = rem - 1016;
        r = (idx2 < 4) ? 0 : 128;
        c0 = 1 + ((idx2 & 3) << 5);
        rq = r;
        rowzero = (r == 0);
    }

    // ---- stage A: s/d, split into bf16 hi/lo, write MFMA-A-operand layout ----
    {
        int j2 = tid >> 3;                  // pair 0..31
        int seg = tid & 7;                  // 16-ch segment
        int ch0 = seg << 4;
        int cp = c0 + j2;
        int cq = (256 - cp) & 255;
        const float4* hp4 = (const float4*)(h + (((b << 16) + (r << 8) + cp) << 7) + ch0);
        const float4* hq4 = (const float4*)(h + (((b << 16) + (rq << 8) + cq) << 7) + ch0);
        float4 P[4] = {hp4[0], hp4[1], hp4[2], hp4[3]};
        float4 Q[4] = {hq4[0], hq4[1], hq4[2], hq4[3]};
        const float* pf = (const float*)P;
        const float* qf = (const float*)Q;
        int kt = seg >> 1;
        int qjb = (seg & 1) << 4;
        #pragma unroll
        for (int e = 0; e < 2; e++) {
            alignas(16) unsigned short sh[8], sl[8], dh[8], dl[8];
            #pragma unroll
            for (int jj = 0; jj < 8; jj++) {
                float pv = pf[e * 8 + jj], qv = qf[e * 8 + jj];
                float s = pv + qv, d = pv - qv;
                unsigned short shi = bf16_rne(s);
                unsigned short dhi = bf16_rne(d);
                sh[jj] = shi; sl[jj] = bf16_rne(s - bf16_tof(shi));
                dh[jj] = dhi; dl[jj] = bf16_rne(d - bf16_tof(dhi));
            }
            int qj = qjb + e * 8;
            *(s8v*)&Abuf[A_IDX(0, kt, 0, j2, qj)] = *(const s8v*)sh;
            *(s8v*)&Abuf[A_IDX(0, kt, 1, j2, qj)] = *(const s8v*)sl;
            *(s8v*)&Abuf[A_IDX(1, kt, 0, j2, qj)] = *(const s8v*)dh;
            *(s8v*)&Abuf[A_IDX(1, kt, 1, j2, qj)] = *(const s8v*)dl;
        }
    }

    int lane = tid & 63;
    int wv = tid >> 6;                      // wave -> 32-col strip
    int l15 = lane & 15;
    int quad = lane >> 4;

    f4v U[2][2], V[2][2];
    #pragma unroll
    for (int mt = 0; mt < 2; mt++)
        #pragma unroll
        for (int nt = 0; nt < 2; nt++) {
            U[mt][nt] = (f4v){0.f, 0.f, 0.f, 0.f};
            V[mt][nt] = (f4v){0.f, 0.f, 0.f, 0.f};
        }

    const uint4* Wg4 = (const uint4*)Wbl;
    for (int kc = 0; kc < 4; kc++) {
        __syncthreads();                    // Abuf ready / prior Wbuf reads done
        {   // stage 32 KB weight chunk (E'hi,E'lo,F'hi,F'lo for 32 k-rows x 128 cols)
            const uint4* src = Wg4 + kc * 2048;   // FIX: chunk = 16384 ushorts = 2048 uint4
            uint4* dst = (uint4*)Wbuf;
            #pragma unroll
            for (int it = 0; it < 8; it++) {
                int off = it * 256 + tid;
                dst[off] = src[off];
            }
        }
        __syncthreads();                    // Wbuf visible

        // A frags: [sd][half][mt]
        s8v a[2][2][2];
        #pragma unroll
        for (int sd = 0; sd < 2; sd++)
            #pragma unroll
            for (int hf = 0; hf < 2; hf++)
                #pragma unroll
                for (int mt = 0; mt < 2; mt++)
                    a[sd][hf][mt] = *(const s8v*)&Abuf[A_IDX(sd, kc, hf, mt * 16 + l15, quad * 8)];

        // B frags: [mat][half][nt]
        s8v bf[2][2][2];
        #pragma unroll
        for (int m2 = 0; m2 < 2; m2++)
            #pragma unroll
            for (int hf = 0; hf < 2; hf++)
                #pragma unroll
                for (int nt = 0; nt < 2; nt++)
                    bf[m2][hf][nt] = *(const s8v*)&Wbuf[W_IDX(m2, hf, quad, wv * 32 + nt * 16 + l15)];

        #pragma unroll
        for (int mt = 0; mt < 2; mt++)
            #pragma unroll
            for (int nt = 0; nt < 2; nt++) {
                U[mt][nt] = __builtin_amdgcn_mfma_f32_16x16x32_bf16(a[0][0][mt], bf[0][0][nt], U[mt][nt], 0, 0, 0);
                V[mt][nt] = __builtin_amdgcn_mfma_f32_16x16x32_bf16(a[1][0][mt], bf[1][0][nt], V[mt][nt], 0, 0, 0);
                U[mt][nt] = __builtin_amdgcn_mfma_f32_16x16x32_bf16(a[0][0][mt], bf[0][1][nt], U[mt][nt], 0, 0, 0);
                V[mt][nt] = __builtin_amdgcn_mfma_f32_16x16x32_bf16(a[1][0][mt], bf[1][1][nt], V[mt][nt], 0, 0, 0);
                U[mt][nt] = __builtin_amdgcn_mfma_f32_16x16x32_bf16(a[0][1][mt], bf[0][0][nt], U[mt][nt], 0, 0, 0);
                V[mt][nt] = __builtin_amdgcn_mfma_f32_16x16x32_bf16(a[1][1][mt], bf[1][0][nt], V[mt][nt], 0, 0, 0);
            }
    }

    // ---- epilogue: U,V co-resident per thread; out_p = U+V, out_q = U-V ----
    #pragma unroll
    for (int mt = 0; mt < 2; mt++)
        #pragma unroll
        for (int nt = 0; nt < 2; nt++) {
            int och = wv * 32 + nt * 16 + l15;
            float cbv = cbl[och];
            #pragma unroll
            for (int rg = 0; rg < 4; rg++) {
                int pair = mt * 16 + quad * 4 + rg;
                int colp = c0 + pair;
                int colq = (256 - colp) & 255;
                float u = U[mt][nt][rg], v = V[mt][nt][rg];
                float bp = u + v + cbv;
                float bq = u - v + cbv;
                if (rowzero) {
                    bp += RBl[(colp << 7) + och];
                    bq += RBl[(colq << 7) + och];
                }
                h[(((b << 16) + (r << 8) + colp) << 7) + och]  = gelu_f(bp);
                h[(((b << 16) + (rq << 8) + colq) << 7) + och] = gelu_f(bq);
            }
        }
}

// y[bp] = gelu(sum_d h[bp][d]*wo[d] + bo); one wave per pixel chunk
__global__ void lin_out_kernel(const float* __restrict__ h, const float* __restrict__ wo,
                               const float* __restrict__ bo, float* __restrict__ out) {
    int gtid = blockIdx.x * 256 + threadIdx.x;
    int wave = gtid >> 6;
    int lane = threadIdx.x & 63;
    float w0 = wo[lane * 2], w1 = wo[lane * 2 + 1];
    float bb = bo[0];
    int px0 = wave * 32;
    for (int px = px0; px < px0 + 32; px++) {
        const float2 v = *(const float2*)(h + (px << 7) + lane * 2);
        float partial = fmaf(v.x, w0, v.y * w1);
        #pragma unroll
        for (int m = 32; m >= 1; m >>= 1) partial += __shfl_xor(partial, m, 64);
        if (lane == 0) out[px] = gelu_f(partial + bb);
    }
}

extern "C" void kernel_launch(void* const* d_in, const int* in_sizes, int n_in,
                              void* d_out, int out_size, void* d_ws, size_t ws_size,
                              hipStream_t stream) {
    const float* x         = (const float*)d_in[0];
    const float* lin_in_w  = (const float*)d_in[1];
    const float* lin_in_b  = (const float*)d_in[2];
    const float* wr        = (const float*)d_in[3];
    const float* wi        = (const float*)d_in[4];
    const float* br        = (const float*)d_in[5];
    const float* bi        = (const float*)d_in[6];
    const float* cw        = (const float*)d_in[7];
    const float* cb        = (const float*)d_in[8];
    const float* lin_out_w = (const float*)d_in[9];
    const float* lin_out_b = (const float*)d_in[10];
    float* out = (float*)d_out;

    size_t need = (size_t)(WS_H_FLOATS + W2_FLOATS + RB_FLOATS) * sizeof(float)
                + (size_t)WBF_USHORTS * sizeof(unsigned short);
    if (ws_size < need) return;
    float* ws = (float*)d_ws;
    float* h  = ws;
    float* W2 = ws + WS_H_FLOATS;
    float* RB = W2 + W2_FLOATS;
    unsigned short* Wbf = (unsigned short*)(RB + RB_FLOATS);

    prep_weights<<<512, 256, 0, stream>>>(wr, wi, cw, W2);
    prep_weights_bf16<<<512, 256, 0, stream>>>(wr, wi, cw, Wbf);
    prep_rowbias<<<512, 256, 0, stream>>>(br, bi, RB);
    lin_in_kernel<<<131072, 256, 0, stream>>>(x, lin_in_w, lin_in_b, h);
    for (int l = 0; l < 4; l++) {
        layer_mfma<<<4100, 256, 0, stream>>>(h, W2 + l * 32768, Wbf + l * 65536,
                                             RB + l * 32768, cb + l * 128);
    }
    lin_out_kernel<<<2048, 256, 0, stream>>>(h, lin_out_w, lin_out_b, out);
}

// Round 4
// 338.795 us; speedup vs baseline: 2.6438x; 1.4364x over previous
//
#include <hip/hip_runtime.h>

// FNO2d fully fused: lin_in -> 4 spectral+conv layers -> lin_out in ONE kernel.
// Key fact: full-mode spectral conv == pair-local mixing (p paired with -p mod 256),
// so the whole network is local on pixel pairs; h never goes to global memory.
#define W2_FLOATS   131072     // 4 layers * 2 (E,F) * 128*128  (fp32, special path uses E')
#define RB_FLOATS   131072     // 4 layers * 256 cols * 128 ch
#define WBF_USHORTS 262144     // 4 layers * 4 chunks * 16384 (split-bf16 B-operand layout)

typedef short s8v __attribute__((ext_vector_type(8)));   // 8 bf16 (4 VGPRs)
typedef float f4v __attribute__((ext_vector_type(4)));   // MFMA acc

__device__ __forceinline__ float gelu_f(float x) {
    return 0.5f * x * (1.0f + erff(x * 0.7071067811865476f));
}
__device__ __forceinline__ unsigned short bf16_rne(float v) {
    unsigned u = __float_as_uint(v);
    unsigned r = u + 0x7FFFu + ((u >> 16) & 1u);
    return (unsigned short)(r >> 16);
}
__device__ __forceinline__ float bf16_tof(unsigned short x) {
    return __uint_as_float(((unsigned)x) << 16);
}

// W2[l][which][i][o] = 0.5*(cw[l][o][i] + (which? wi : wr)[l][i][o])  (fp32, special path)
__global__ void prep_weights(const float* __restrict__ wr, const float* __restrict__ wi,
                             const float* __restrict__ cw, float* __restrict__ W2) {
    int idx = blockIdx.x * 256 + threadIdx.x;       // 131072
    int l = idx >> 15;
    int which = (idx >> 14) & 1;
    int i = (idx >> 7) & 127;
    int o = idx & 127;
    const float* w = which ? wi : wr;
    W2[idx] = 0.5f * (cw[(l << 14) + (o << 7) + i] + w[(l << 14) + (i << 7) + o]);
}

// Split-bf16 weights in B-operand layout.
// Wbf[l][kc][mat][half][quad][col][j]; k = kc*32 + quad*8 + j (input ch), col = out ch.
__global__ void prep_weights_bf16(const float* __restrict__ wr, const float* __restrict__ wi,
                                  const float* __restrict__ cw, unsigned short* __restrict__ Wbf) {
    int t = blockIdx.x * 256 + threadIdx.x;         // 131072 = 4*4*2*4*128*8
    int j    = t & 7;
    int col  = (t >> 3) & 127;
    int quad = (t >> 10) & 3;
    int m2   = (t >> 12) & 1;
    int kc   = (t >> 13) & 3;
    int l    = t >> 15;
    int k = kc * 32 + quad * 8 + j;
    const float* w = m2 ? wi : wr;
    float v = 0.5f * (cw[(l << 14) + (col << 7) + k] + w[(l << 14) + (k << 7) + col]);
    unsigned short hi = bf16_rne(v);
    unsigned short lo = bf16_rne(v - bf16_tof(hi));
    int base = (l * 4 + kc) * 16384;
    int idx_hi = base + (((m2 * 2 + 0) * 4 + quad) * 128 + col) * 8 + j;
    int idx_lo = base + (((m2 * 2 + 1) * 4 + quad) * 128 + col) * 8 + j;
    Wbf[idx_hi] = hi;
    Wbf[idx_lo] = lo;
}

// RB[l][c][o]: spatial map of the per-frequency constant bias (row n1==0 only).
__global__ void prep_rowbias(const float* __restrict__ br, const float* __restrict__ bi,
                             float* __restrict__ RB) {
    int idx = blockIdx.x * 256 + threadIdx.x;       // 131072 = 4*256*128
    int l = idx >> 15;
    int c = (idx >> 7) & 255;
    int o = idx & 127;
    float v;
    if (c == 0) {
        v = br[(l << 7) + o];
    } else {
        float s = 0.0f;
        for (int k = 1; k < 128; k++) {
            int m = (k * c) & 255;
            s += sinf(0.024543692952156857f * (float)m);  // pi/128
        }
        v = -bi[(l << 7) + o] * s * 0.0078125f;
    }
    RB[idx] = v;
}

// Abuf layout (ushort): [sd2][kt4][half2][pair32][qj(APAD)]; qj = k&31.
// APAD=40 (row=80B): restage b16 scatter lands 2 lanes/bank (free); b128 frag
// reads stay at the b128 floor; 16B alignment preserved (qj offsets 0/8/16/24).
#define APAD 40
#define A_IDX(sd, kt, hf, pair, qj) ((((((sd)*4 + (kt))*2 + (hf))*32 + (pair))*APAD) + (qj))
// Wbf chunk-relative index: [mat2][half2][quad4][col128][j8]
#define W_IDX(m2, hf, quad, col) (((((m2)*2 + (hf))*4 + (quad))*128 + (col))*8)

__global__ __launch_bounds__(256, 2) void fno_fused(
        const float* __restrict__ x,
        const float* __restrict__ w_in, const float* __restrict__ b_in,
        const unsigned short* __restrict__ Wbf,
        const float* __restrict__ W2,
        const float* __restrict__ RB,
        const float* __restrict__ cb,
        const float* __restrict__ wo, const float* __restrict__ bo,
        float* __restrict__ out)
{
    __shared__ unsigned short Abuf[2 * 4 * 2 * 32 * APAD];   // 40 KB

    int bid = blockIdx.x;
    int tid = threadIdx.x;

    if (bid >= 4096) {
        // --- special: self-paired pixels (b,0,0) and (b,128,0), fp32 path, fully fused ---
        float* Hs = (float*)Abuf;
        int b2 = bid - 4096;
        int o = tid & 127;
        int rowp = (tid < 128) ? 0 : 128;
        float acc = b_in[o];
        #pragma unroll
        for (int c = 0; c < 3; c++)
            acc = fmaf(x[((b2 * 3 + c) << 16) + (rowp << 8)], w_in[c * 128 + o], acc);
        float hval = gelu_f(acc);
        for (int l = 0; l < 4; l++) {
            __syncthreads();
            Hs[tid] = hval;
            __syncthreads();
            const float* W2l = W2 + l * 32768;          // E' (which=0) plane
            const float* hb = Hs + ((tid < 128) ? 0 : 128);
            float a2 = 0.0f;
            for (int i = 0; i < 128; i++) a2 = fmaf(W2l[(i << 7) + o], hb[i], a2);
            a2 = 2.0f * a2 + cb[l * 128 + o];
            if (tid < 128) a2 += RB[l * 32768 + o];     // row 0, col 0
            hval = gelu_f(a2);
        }
        __syncthreads();
        Hs[tid] = hval * wo[o];
        __syncthreads();
        #pragma unroll
        for (int off = 64; off >= 1; off >>= 1) {
            if ((tid & 127) < off) Hs[tid] += Hs[tid + off];
            __syncthreads();
        }
        if ((tid & 127) == 0) out[(b2 << 16) + (rowp << 8)] = gelu_f(Hs[tid] + bo[0]);
        return;
    }

    int b = bid >> 10;
    int rem = bid & 1023;
    int r, c0, rq;
    bool rowzero;
    if (rem < 1016) {
        r = 1 + (rem >> 3);
        c0 = (rem & 7) << 5;
        rq = 256 - r;
        rowzero = false;
    } else {
        int idx2 = rem - 1016;
        r = (idx2 < 4) ? 0 : 128;
        c0 = 1 + ((idx2 & 3) << 5);
        rq = r;
        rowzero = (r == 0);
    }

    // ---- lin_in + stage A: h = gelu(x*Win+bin); s/d split-bf16 into Abuf ----
    {
        int j2 = tid >> 3;                  // pair 0..31
        int seg = tid & 7;                  // 16-ch segment
        int ch0 = seg << 4;
        int cp = c0 + j2;
        int cq = (256 - cp) & 255;
        float xp[3], xq[3];
        #pragma unroll
        for (int c = 0; c < 3; c++) {
            xp[c] = x[((b * 3 + c) << 16) + (r << 8) + cp];
            xq[c] = x[((b * 3 + c) << 16) + (rq << 8) + cq];
        }
        int kt = seg >> 1;
        int qjb = (seg & 1) << 4;
        #pragma unroll
        for (int e = 0; e < 2; e++) {
            alignas(16) unsigned short sh[8], sl[8], dh[8], dl[8];
            #pragma unroll
            for (int jj = 0; jj < 8; jj++) {
                int d = ch0 + e * 8 + jj;
                float ap = b_in[d], aq = b_in[d];
                #pragma unroll
                for (int c = 0; c < 3; c++) {
                    float w = w_in[c * 128 + d];
                    ap = fmaf(xp[c], w, ap);
                    aq = fmaf(xq[c], w, aq);
                }
                float hp = gelu_f(ap), hq = gelu_f(aq);
                float s = hp + hq, dd = hp - hq;
                unsigned short shi = bf16_rne(s);
                unsigned short dhi = bf16_rne(dd);
                sh[jj] = shi; sl[jj] = bf16_rne(s - bf16_tof(shi));
                dh[jj] = dhi; dl[jj] = bf16_rne(dd - bf16_tof(dhi));
            }
            int qj = qjb + e * 8;
            *(s8v*)&Abuf[A_IDX(0, kt, 0, j2, qj)] = *(const s8v*)sh;
            *(s8v*)&Abuf[A_IDX(0, kt, 1, j2, qj)] = *(const s8v*)sl;
            *(s8v*)&Abuf[A_IDX(1, kt, 0, j2, qj)] = *(const s8v*)dh;
            *(s8v*)&Abuf[A_IDX(1, kt, 1, j2, qj)] = *(const s8v*)dl;
        }
    }

    int lane = tid & 63;
    int wv = tid >> 6;                      // wave -> 32-col (out-ch) strip
    int l15 = lane & 15;
    int quad = lane >> 4;
    int och0 = wv * 32 + l15;               // nt=0 out-ch
    int och1 = och0 + 16;                   // nt=1 out-ch
    float wo0 = wo[och0], wo1 = wo[och1];

    float pp[8], pq[8];                     // lin_out partials, idx = mt*4+rg
    #pragma unroll
    for (int i = 0; i < 8; i++) { pp[i] = 0.0f; pq[i] = 0.0f; }

    for (int l = 0; l < 4; l++) {
        __syncthreads();                    // Abuf writes visible

        f4v U[2][2], V[2][2];
        #pragma unroll
        for (int mt = 0; mt < 2; mt++)
            #pragma unroll
            for (int nt = 0; nt < 2; nt++) {
                U[mt][nt] = (f4v){0.f, 0.f, 0.f, 0.f};
                V[mt][nt] = (f4v){0.f, 0.f, 0.f, 0.f};
            }

        const unsigned short* Wl = Wbf + l * 65536;
        #pragma unroll
        for (int kc = 0; kc < 4; kc++) {
            // B frags straight from global (L2-resident): [mat][half][nt]
            s8v bf[2][2][2];
            #pragma unroll
            for (int m2 = 0; m2 < 2; m2++)
                #pragma unroll
                for (int hf = 0; hf < 2; hf++)
                    #pragma unroll
                    for (int nt = 0; nt < 2; nt++)
                        bf[m2][hf][nt] = *(const s8v*)&Wl[kc * 16384 +
                                W_IDX(m2, hf, quad, wv * 32 + nt * 16 + l15)];
            // A frags from LDS: [sd][half][mt]
            s8v a[2][2][2];
            #pragma unroll
            for (int sd = 0; sd < 2; sd++)
                #pragma unroll
                for (int hf = 0; hf < 2; hf++)
                    #pragma unroll
                    for (int mt = 0; mt < 2; mt++)
                        a[sd][hf][mt] = *(const s8v*)&Abuf[A_IDX(sd, kc, hf, mt * 16 + l15, quad * 8)];

            #pragma unroll
            for (int mt = 0; mt < 2; mt++)
                #pragma unroll
                for (int nt = 0; nt < 2; nt++) {
                    U[mt][nt] = __builtin_amdgcn_mfma_f32_16x16x32_bf16(a[0][0][mt], bf[0][0][nt], U[mt][nt], 0, 0, 0);
                    V[mt][nt] = __builtin_amdgcn_mfma_f32_16x16x32_bf16(a[1][0][mt], bf[1][0][nt], V[mt][nt], 0, 0, 0);
                    U[mt][nt] = __builtin_amdgcn_mfma_f32_16x16x32_bf16(a[0][0][mt], bf[0][1][nt], U[mt][nt], 0, 0, 0);
                    V[mt][nt] = __builtin_amdgcn_mfma_f32_16x16x32_bf16(a[1][0][mt], bf[1][1][nt], V[mt][nt], 0, 0, 0);
                    U[mt][nt] = __builtin_amdgcn_mfma_f32_16x16x32_bf16(a[0][1][mt], bf[0][0][nt], U[mt][nt], 0, 0, 0);
                    V[mt][nt] = __builtin_amdgcn_mfma_f32_16x16x32_bf16(a[1][1][mt], bf[1][0][nt], V[mt][nt], 0, 0, 0);
                }
        }

        __syncthreads();                    // all Abuf reads done before restage

        // ---- epilogue: out_p = gelu(u+v+bias), out_q = gelu(u-v+bias) ----
        const float* RBl = RB + l * 32768;
        #pragma unroll
        for (int mt = 0; mt < 2; mt++)
            #pragma unroll
            for (int nt = 0; nt < 2; nt++) {
                int och = nt ? och1 : och0;
                float cbv = cb[l * 128 + och];
                #pragma unroll
                for (int rg = 0; rg < 4; rg++) {
                    int pair = mt * 16 + quad * 4 + rg;
                    int colp = c0 + pair;
                    int colq = (256 - colp) & 255;
                    float u = U[mt][nt][rg], v = V[mt][nt][rg];
                    float bp = u + v + cbv;
                    float bq = u - v + cbv;
                    if (rowzero) {
                        bp += RBl[(colp << 7) + och];
                        bq += RBl[(colq << 7) + och];
                    }
                    float hp = gelu_f(bp), hq = gelu_f(bq);
                    if (l < 3) {
                        // restage for next layer: k = och -> kt=wv, qj = nt*16+l15
                        float s = hp + hq, dd = hp - hq;
                        unsigned short shi = bf16_rne(s);
                        unsigned short dhi = bf16_rne(dd);
                        int qj = nt * 16 + l15;
                        Abuf[A_IDX(0, wv, 0, pair, qj)] = shi;
                        Abuf[A_IDX(0, wv, 1, pair, qj)] = bf16_rne(s - bf16_tof(shi));
                        Abuf[A_IDX(1, wv, 0, pair, qj)] = dhi;
                        Abuf[A_IDX(1, wv, 1, pair, qj)] = bf16_rne(dd - bf16_tof(dhi));
                    } else {
                        float w = nt ? wo1 : wo0;
                        pp[mt * 4 + rg] = fmaf(hp, w, pp[mt * 4 + rg]);
                        pq[mt * 4 + rg] = fmaf(hq, w, pq[mt * 4 + rg]);
                    }
                }
            }
    }

    // ---- lin_out: reduce partials over l15 (16 lanes) then across waves via LDS ----
    #pragma unroll
    for (int i = 0; i < 8; i++) {
        #pragma unroll
        for (int m = 1; m <= 8; m <<= 1) {
            pp[i] += __shfl_xor(pp[i], m, 64);
            pq[i] += __shfl_xor(pq[i], m, 64);
        }
    }
    float* Pb = (float*)Abuf;               // [2][32 pairs][4 wv]; Abuf reads all done
    if (l15 == 0) {
        #pragma unroll
        for (int mt = 0; mt < 2; mt++)
            #pragma unroll
            for (int rg = 0; rg < 4; rg++) {
                int pair = mt * 16 + quad * 4 + rg;
                Pb[(pair << 2) + wv]        = pp[mt * 4 + rg];
                Pb[128 + (pair << 2) + wv]  = pq[mt * 4 + rg];
            }
    }
    __syncthreads();
    if (tid < 64) {
        int pqsel = tid >> 5;
        int pair = tid & 31;
        const float* pb = Pb + pqsel * 128 + (pair << 2);
        float ssum = pb[0] + pb[1] + pb[2] + pb[3] + bo[0];
        int colp = c0 + pair;
        int col = pqsel ? ((256 - colp) & 255) : colp;
        int row = pqsel ? rq : r;
        out[(b << 16) + (row << 8) + col] = gelu_f(ssum);
    }
}

extern "C" void kernel_launch(void* const* d_in, const int* in_sizes, int n_in,
                              void* d_out, int out_size, void* d_ws, size_t ws_size,
                              hipStream_t stream) {
    const float* x         = (const float*)d_in[0];
    const float* lin_in_w  = (const float*)d_in[1];
    const float* lin_in_b  = (const float*)d_in[2];
    const float* wr        = (const float*)d_in[3];
    const float* wi        = (const float*)d_in[4];
    const float* br        = (const float*)d_in[5];
    const float* bi        = (const float*)d_in[6];
    const float* cw        = (const float*)d_in[7];
    const float* cb        = (const float*)d_in[8];
    const float* lin_out_w = (const float*)d_in[9];
    const float* lin_out_b = (const float*)d_in[10];
    float* out = (float*)d_out;

    size_t need = (size_t)(W2_FLOATS + RB_FLOATS) * sizeof(float)
                + (size_t)WBF_USHORTS * sizeof(unsigned short);
    if (ws_size < need) return;
    float* ws = (float*)d_ws;
    float* W2 = ws;
    float* RB = W2 + W2_FLOATS;
    unsigned short* Wbf = (unsigned short*)(RB + RB_FLOATS);

    prep_weights<<<512, 256, 0, stream>>>(wr, wi, cw, W2);
    prep_weights_bf16<<<512, 256, 0, stream>>>(wr, wi, cw, Wbf);
    prep_rowbias<<<512, 256, 0, stream>>>(br, bi, RB);
    fno_fused<<<4100, 256, 0, stream>>>(x, lin_in_w, lin_in_b, Wbf, W2, RB,
                                        cb, lin_out_w, lin_out_b, out);
}